// Round 1
// 797.609 us; speedup vs baseline: 1.2628x; 1.2628x over previous
//
#include <hip/hip_runtime.h>
#include <stdint.h>

// Problem constants
#define MM 32768
#define KK 1024
#define NN 4096

#define BM 128
#define BN 128
#define BK 64

typedef __attribute__((ext_vector_type(4))) float floatx4;
typedef long i64;

// ---- fp8 e4m3fn pack via HW cvt (RNE, OCP on gfx950) ----
__device__ __forceinline__ uint32_t pack4_fp8(float a, float b, float c, float d) {
  int v = 0;
  v = __builtin_amdgcn_cvt_pk_fp8_f32(a, b, v, false);  // bytes 0,1
  v = __builtin_amdgcn_cvt_pk_fp8_f32(c, d, v, true);   // bytes 2,3
  return (uint32_t)v;
}

// ---- async global->LDS, 16B per lane ----
__device__ __forceinline__ void gld_lds16(const void* g, void* l) {
  __builtin_amdgcn_global_load_lds(
      (const __attribute__((address_space(1))) uint32_t*)g,
      (__attribute__((address_space(3))) uint32_t*)l, 16, 0, 0);
}

// ---- quantize x: M*K fp32 -> fp8, 16 elems/thread ----
__global__ __launch_bounds__(256) void quant_x_kernel(const float* __restrict__ x,
                                                      uint8_t* __restrict__ o) {
  size_t i = ((size_t)blockIdx.x * 256 + threadIdx.x) * 16;
  const float4* xp = (const float4*)(x + i);
  float4 f0 = xp[0], f1 = xp[1], f2 = xp[2], f3 = xp[3];
  uint4 o4;
  o4.x = pack4_fp8(f0.x, f0.y, f0.z, f0.w);
  o4.y = pack4_fp8(f1.x, f1.y, f1.z, f1.w);
  o4.z = pack4_fp8(f2.x, f2.y, f2.z, f2.w);
  o4.w = pack4_fp8(f3.x, f3.y, f3.z, f3.w);
  *(uint4*)(o + i) = o4;
}

// ---- quantize + transpose w: (K,N) fp32 -> (N,K) fp8 ----
// grid: (N/256, K/16); coalesced column reads, 16B row writes.
__global__ __launch_bounds__(256) void quant_w_kernel(const float* __restrict__ w,
                                                      uint8_t* __restrict__ o) {
  int n  = blockIdx.x * 256 + threadIdx.x;
  int k0 = blockIdx.y * 16;
  uint32_t p[4];
#pragma unroll
  for (int q = 0; q < 4; ++q) {
    float a = w[(size_t)(k0 + q * 4 + 0) * NN + n];
    float b = w[(size_t)(k0 + q * 4 + 1) * NN + n];
    float c = w[(size_t)(k0 + q * 4 + 2) * NN + n];
    float d = w[(size_t)(k0 + q * 4 + 3) * NN + n];
    p[q] = pack4_fp8(a, b, c, d);
  }
  *(uint4*)(o + (size_t)n * KK + k0) = make_uint4(p[0], p[1], p[2], p[3]);
}

// ---- fp8 GEMM: C(M,N) = A8(M,K) * B8T(N,K)^T, fp32 out ----
// 128x128 tile / block of 256 threads (4 waves, each 64x64 = 4x4 MFMA tiles)
//
// LDS bank-conflict fix (T2 adapted to global_load_lds, rule #21):
//   16B-granular XOR swizzle: LDS(row, c16) holds global A[row][c16 ^ ((row>>1)&3)].
//   - staging: LDS dest stays LINEAR (tid*16); the GLOBAL source column is
//     pre-swizzled per staging thread (each 16B granule stays contiguous).
//   - read: slot16' = slot16 ^ ((r>>1)&3) -> wave's 64 ds_read_b64 lanes spread
//     uniformly over all 16 bank-pairs (4 lanes/pair = HW minimum, conflict-free).
__global__ __launch_bounds__(256) void gemm_fp8_kernel(const uint8_t* __restrict__ A,
                                                       const uint8_t* __restrict__ Bt,
                                                       float* __restrict__ C) {
  __shared__ uint8_t As[BM * BK];  // [m][k-swizzled] 8 KB
  __shared__ uint8_t Bs[BN * BK];  // [n][k-swizzled] 8 KB

  const int tid  = threadIdx.x;
  const int lane = tid & 63;
  const int wv   = tid >> 6;
  const int wr   = (wv >> 1) * 64;  // wave row offset in tile
  const int wc   = (wv & 1) * 64;   // wave col offset in tile
  const int quad = lane >> 4;
  const int r    = lane & 15;

  // XCD-aware chunked swizzle (m157): 8192 wgs, 8 XCDs -> 1024-wg chunks.
  // Dispatch round-robins XCDs by orig id; remap so each XCD gets a contiguous
  // range of tiles (n-fast, so an XCD's blocks share A-panels in its L2).
  const int lid = (int)blockIdx.x;                 // 0..8191
  const int swz = (lid & 7) * 1024 + (lid >> 3);   // bijective (8192 % 8 == 0)
  const long bm = (long)(swz >> 5) * BM;           // 256 m-tiles
  const long bn = (long)(swz & 31) * BN;           // 32 n-tiles

  // staging: thread t fills LDS bytes [t*16, t*16+16) (wave-uniform base + lane*16).
  // LDS slot (row=t>>2, c16=t&3) <- global 16B column (c16 ^ ((row>>1)&3)).
  const int srow = tid >> 2;                        // 0..63
  const int sc16 = tid & 3;
  const int scol = ((sc16 ^ ((srow >> 1) & 3)) << 4);  // swizzled source column
  // rows srow and srow+64 share the same swizzle ((row>>1)&3 invariant mod 64)
  const uint8_t* Ag = A + (bm + srow) * KK + scol;
  const uint8_t* Bg = Bt + (bn + srow) * KK + scol;
  uint8_t* Al = &As[tid * 16];
  uint8_t* Bl = &Bs[tid * 16];

  floatx4 acc[4][4] = {};

  // read-side swizzle: row = (wr|wc) + i*16 + r, and (wr+i*16) % 16 == 0,
  // so ((row>>1)&3) == ((r>>1)&3) for every fragment row this lane touches.
  const int e = (r >> 1) & 3;

  for (int k0 = 0; k0 < KK; k0 += BK) {
    gld_lds16(Ag + k0, Al);
    gld_lds16(Ag + 64 * KK + k0, Al + 4096);
    gld_lds16(Bg + k0, Bl);
    gld_lds16(Bg + 64 * KK + k0, Bl + 4096);
    __syncthreads();  // compiler emits vmcnt(0) drain before s_barrier

#pragma unroll
    for (int kk = 0; kk < 2; ++kk) {
      // desired global byte col = kk*32 + quad*8 -> 16B slot = kk*2 + (quad>>1),
      // within-slot 8B half = quad&1; apply XOR swizzle to the slot index.
      const int co = (((kk * 2 + (quad >> 1)) ^ e) << 4) + ((quad & 1) << 3);
      i64 af[4], bf[4];
#pragma unroll
      for (int i = 0; i < 4; ++i)
        af[i] = *(const i64*)&As[(wr + i * 16 + r) * BK + co];
#pragma unroll
      for (int j = 0; j < 4; ++j)
        bf[j] = *(const i64*)&Bs[(wc + j * 16 + r) * BK + co];
#pragma unroll
      for (int i = 0; i < 4; ++i)
#pragma unroll
        for (int j = 0; j < 4; ++j)
          acc[i][j] = __builtin_amdgcn_mfma_f32_16x16x32_fp8_fp8(af[i], bf[j], acc[i][j], 0, 0, 0);
    }
    __syncthreads();
  }

  // epilogue: C/D layout col=lane&15, row=quad*4+reg (dtype-independent, m121-128)
#pragma unroll
  for (int i = 0; i < 4; ++i) {
    const long row0 = bm + wr + i * 16 + quad * 4;
#pragma unroll
    for (int j = 0; j < 4; ++j) {
      const long col = bn + wc + j * 16 + r;
#pragma unroll
      for (int v = 0; v < 4; ++v) C[(row0 + v) * NN + col] = acc[i][j][v];
    }
  }
}

extern "C" void kernel_launch(void* const* d_in, const int* in_sizes, int n_in,
                              void* d_out, int out_size, void* d_ws, size_t ws_size,
                              hipStream_t stream) {
  const float* x = (const float*)d_in[0];  // (M,K) fp32
  const float* w = (const float*)d_in[1];  // (K,N) fp32
  float* out = (float*)d_out;              // (M,N) fp32

  uint8_t* x8  = (uint8_t*)d_ws;                    // 32 MB
  uint8_t* w8t = x8 + (size_t)MM * KK;              // 4 MB, (N,K)

  quant_x_kernel<<<(MM * (size_t)KK) / (256 * 16), 256, 0, stream>>>(x, x8);
  quant_w_kernel<<<dim3(NN / 256, KK / 16), 256, 0, stream>>>(w, w8t);
  gemm_fp8_kernel<<<(MM / BM) * (NN / BN), 256, 0, stream>>>(x8, w8t, out);
}

// Round 2
// 763.453 us; speedup vs baseline: 1.3193x; 1.0447x over previous
//
#include <hip/hip_runtime.h>
#include <stdint.h>

// Problem constants
#define MM 32768
#define KK 1024
#define NN 4096

#define BM 128
#define BN 128
#define BK 128

typedef __attribute__((ext_vector_type(4))) float floatx4;
typedef __attribute__((ext_vector_type(8))) int intx8;

// ---- fp8 e4m3fn pack via HW cvt (RNE, OCP on gfx950) ----
__device__ __forceinline__ uint32_t pack4_fp8(float a, float b, float c, float d) {
  int v = 0;
  v = __builtin_amdgcn_cvt_pk_fp8_f32(a, b, v, false);  // bytes 0,1
  v = __builtin_amdgcn_cvt_pk_fp8_f32(c, d, v, true);   // bytes 2,3
  return (uint32_t)v;
}

// ---- async global->LDS, 16B per lane ----
__device__ __forceinline__ void gld_lds16(const void* g, void* l) {
  __builtin_amdgcn_global_load_lds(
      (const __attribute__((address_space(1))) uint32_t*)g,
      (__attribute__((address_space(3))) uint32_t*)l, 16, 0, 0);
}

// ---- quantize x: M*K fp32 -> fp8, 16 elems/thread ----
__global__ __launch_bounds__(256) void quant_x_kernel(const float* __restrict__ x,
                                                      uint8_t* __restrict__ o) {
  size_t i = ((size_t)blockIdx.x * 256 + threadIdx.x) * 16;
  const float4* xp = (const float4*)(x + i);
  float4 f0 = xp[0], f1 = xp[1], f2 = xp[2], f3 = xp[3];
  uint4 o4;
  o4.x = pack4_fp8(f0.x, f0.y, f0.z, f0.w);
  o4.y = pack4_fp8(f1.x, f1.y, f1.z, f1.w);
  o4.z = pack4_fp8(f2.x, f2.y, f2.z, f2.w);
  o4.w = pack4_fp8(f3.x, f3.y, f3.z, f3.w);
  *(uint4*)(o + i) = o4;
}

// ---- quantize + transpose w: (K,N) fp32 -> (N,K) fp8 ----
__global__ __launch_bounds__(256) void quant_w_kernel(const float* __restrict__ w,
                                                      uint8_t* __restrict__ o) {
  int n  = blockIdx.x * 256 + threadIdx.x;
  int k0 = blockIdx.y * 16;
  uint32_t p[4];
#pragma unroll
  for (int q = 0; q < 4; ++q) {
    float a = w[(size_t)(k0 + q * 4 + 0) * NN + n];
    float b = w[(size_t)(k0 + q * 4 + 1) * NN + n];
    float c = w[(size_t)(k0 + q * 4 + 2) * NN + n];
    float d = w[(size_t)(k0 + q * 4 + 3) * NN + n];
    p[q] = pack4_fp8(a, b, c, d);
  }
  *(uint4*)(o + (size_t)n * KK + k0) = make_uint4(p[0], p[1], p[2], p[3]);
}

// ---- MX-fp8 GEMM: C(M,N) = A8(M,K) * B8T(N,K)^T, fp32 out ----
// 128x128 tile / 256 threads (4 waves, each 64x64 = 4x4 MFMA sub-tiles).
// mfma_scale_f32_16x16x128_f8f6f4 with e8m0 scale 127 (=1.0) -> exact fp8
// products at ~2x the non-scaled fp8 rate (m148: 995->1628 TF at this structure).
//
// LDS swizzle (BK=128 -> row stride = 128 B = full bank span):
//   16B-granule XOR: LDS(row, g) holds global granule g ^ (row&7).
//   - staging: LDS dest LINEAR (tid*16, global_load_lds constraint);
//     the GLOBAL source column is pre-swizzled per staging thread.
//   - read: lane wants granules {2q, 2q+1} at row (..+r); reads LDS granules
//     ^(r&7) -> per ds_read_b128 the 16 lanes of a (q)-group spread over all
//     8 granules, 2 lanes each = conflict-free (2-way is free, m136).
__global__ __launch_bounds__(256) void gemm_fp8_kernel(const uint8_t* __restrict__ A,
                                                       const uint8_t* __restrict__ Bt,
                                                       float* __restrict__ C) {
  __shared__ uint8_t As[BM * BK];  // 16 KB
  __shared__ uint8_t Bs[BN * BK];  // 16 KB

  const int tid  = threadIdx.x;
  const int lane = tid & 63;
  const int wv   = tid >> 6;
  const int wr   = (wv >> 1) * 64;  // wave row offset in tile
  const int wc   = (wv & 1) * 64;   // wave col offset in tile
  const int quad = lane >> 4;
  const int r    = lane & 15;

  // XCD-aware chunked swizzle (m157): 8192 wgs, 8 XCDs -> 1024-wg chunks.
  const int lid = (int)blockIdx.x;                 // 0..8191
  const int swz = (lid & 7) * 1024 + (lid >> 3);   // bijective (8192 % 8 == 0)
  const long bm = (long)(swz >> 5) * BM;           // 256 m-tiles
  const long bn = (long)(swz & 31) * BN;           // 32 n-tiles

  // staging: thread t fills LDS bytes [t*16, t*16+16) = slot (row=t>>3, g=t&7);
  // source column = (g ^ (row&7))*16. (row&7) invariant under +32-row blocks.
  const int sr   = tid >> 3;  // 0..31
  const int sg   = tid & 7;
  const int scol = (sg ^ (sr & 7)) << 4;
  const uint8_t* Ag = A + (bm + sr) * KK + scol;
  const uint8_t* Bg = Bt + (bn + sr) * KK + scol;
  uint8_t* Al = &As[tid * 16];
  uint8_t* Bl = &Bs[tid * 16];

  floatx4 acc[4][4] = {};

  // read-side swizzle key: fragment rows are (wr|wc) + i*16 + r, and
  // (wr + i*16) % 16 == 0, so (row&7) == (r&7) for every row this lane reads.
  const int e   = r & 7;
  const int gA0 = (((quad << 1) | 0) ^ e) << 4;  // byte offset of k-half 0
  const int gA1 = (((quad << 1) | 1) ^ e) << 4;  // byte offset of k-half 1

  for (int k0 = 0; k0 < KK; k0 += BK) {
#pragma unroll
    for (int blk = 0; blk < 4; ++blk) {
      gld_lds16(Ag + k0 + (size_t)blk * 32 * KK, Al + blk * 4096);
      gld_lds16(Bg + k0 + (size_t)blk * 32 * KK, Bl + blk * 4096);
    }
    __syncthreads();  // vmcnt(0) drain before s_barrier (compiler-emitted)

    intx8 af[4], bf[4];
#pragma unroll
    for (int i = 0; i < 4; ++i) {
      const uint8_t* pa = &As[(wr + i * 16 + r) * BK];
      union { intx8 v; int4 q[2]; } u;
      u.q[0] = *(const int4*)(pa + gA0);
      u.q[1] = *(const int4*)(pa + gA1);
      af[i] = u.v;
    }
#pragma unroll
    for (int j = 0; j < 4; ++j) {
      const uint8_t* pb = &Bs[(wc + j * 16 + r) * BK];
      union { intx8 v; int4 q[2]; } u;
      u.q[0] = *(const int4*)(pb + gA0);
      u.q[1] = *(const int4*)(pb + gA1);
      bf[j] = u.v;
    }
#pragma unroll
    for (int i = 0; i < 4; ++i)
#pragma unroll
      for (int j = 0; j < 4; ++j)
        // cbsz=0 (A fp8 e4m3), blgp=0 (B fp8 e4m3), scales = e8m0 127 = 1.0
        acc[i][j] = __builtin_amdgcn_mfma_scale_f32_16x16x128_f8f6f4(
            af[i], bf[j], acc[i][j], 0, 0, 0, 127, 0, 127);
    __syncthreads();
  }

  // epilogue: C/D layout col=lane&15, row=quad*4+reg (shape-determined, m121-128)
#pragma unroll
  for (int i = 0; i < 4; ++i) {
    const long row0 = bm + wr + i * 16 + quad * 4;
#pragma unroll
    for (int j = 0; j < 4; ++j) {
      const long col = bn + wc + j * 16 + r;
#pragma unroll
      for (int v = 0; v < 4; ++v) C[(row0 + v) * NN + col] = acc[i][j][v];
    }
  }
}

extern "C" void kernel_launch(void* const* d_in, const int* in_sizes, int n_in,
                              void* d_out, int out_size, void* d_ws, size_t ws_size,
                              hipStream_t stream) {
  const float* x = (const float*)d_in[0];  // (M,K) fp32
  const float* w = (const float*)d_in[1];  // (K,N) fp32
  float* out = (float*)d_out;              // (M,N) fp32

  uint8_t* x8  = (uint8_t*)d_ws;                    // 32 MB
  uint8_t* w8t = x8 + (size_t)MM * KK;              // 4 MB, (N,K)

  quant_x_kernel<<<(MM * (size_t)KK) / (256 * 16), 256, 0, stream>>>(x, x8);
  quant_w_kernel<<<dim3(NN / 256, KK / 16), 256, 0, stream>>>(w, w8t);
  gemm_fp8_kernel<<<(MM / BM) * (NN / BN), 256, 0, stream>>>(x8, w8t, out);
}